// Round 1
// baseline (4087.274 us; speedup 1.0000x reference)
//
#include <hip/hip_runtime.h>
#include <math.h>

#define NN 100000
#define NE 3200000
#define NR 90

// ---------------- count per (dst, rel) ----------------
__global__ void count_kernel(const int* __restrict__ dst,
                             const int* __restrict__ etype,
                             unsigned int* __restrict__ cnt) {
    int e = blockIdx.x * blockDim.x + threadIdx.x;
    if (e >= NE) return;
    atomicAdd(&cnt[dst[e] * NR + etype[e]], 1u);
}

// ---------------- layer 1 edge pass: in=4 (2 blocks x 2), out=8 (2 x 4), mean ----------------
__global__ void edge1_kernel(const int* __restrict__ src, const int* __restrict__ dst,
                             const int* __restrict__ etype,
                             const float* __restrict__ x, const float* __restrict__ w1,
                             const unsigned int* __restrict__ cnt,
                             float* __restrict__ h1) {
    int e = blockIdx.x * blockDim.x + threadIdx.x;
    if (e >= NE) return;
    int s = src[e], d = dst[e], t = etype[e];
    float norm = 1.0f / fmaxf((float)cnt[d * NR + t], 1.0f);
    const float* xs = x + (size_t)s * 4;
    const float* w = w1 + (size_t)t * 16;   // [b][i][o] = [2][2][4]
    float x0 = xs[0], x1 = xs[1], x2 = xs[2], x3 = xs[3];
    float* out = h1 + (size_t)d * 8;
#pragma unroll
    for (int o = 0; o < 4; o++)
        atomicAdd(&out[o], (x0 * w[o] + x1 * w[4 + o]) * norm);
#pragma unroll
    for (int o = 0; o < 4; o++)
        atomicAdd(&out[4 + o], (x2 * w[8 + o] + x3 * w[12 + o]) * norm);
}

// ---------------- layer 1 node pass: h1 = relu(h1 + x@root1 + b1) ----------------
__global__ void node1_kernel(const float* __restrict__ x, const float* __restrict__ root1,
                             const float* __restrict__ b1, float* __restrict__ h1) {
    int n = blockIdx.x * blockDim.x + threadIdx.x;
    if (n >= NN) return;
    const float* xs = x + (size_t)n * 4;
    float* h = h1 + (size_t)n * 8;
    float xv[4];
#pragma unroll
    for (int i = 0; i < 4; i++) xv[i] = xs[i];
#pragma unroll
    for (int j = 0; j < 8; j++) {
        float v = h[j] + b1[j];
#pragma unroll
        for (int i = 0; i < 4; i++) v += xv[i] * root1[i * 8 + j];
        h[j] = fmaxf(v, 0.0f);
    }
}

// ---------------- layer 2 edge pass: in=8 (4 x 2), out=12 (4 x 3), add ----------------
__global__ void edge2_kernel(const int* __restrict__ src, const int* __restrict__ dst,
                             const int* __restrict__ etype,
                             const float* __restrict__ h1, const float* __restrict__ w2,
                             float* __restrict__ h2) {
    int e = blockIdx.x * blockDim.x + threadIdx.x;
    if (e >= NE) return;
    int s = src[e], d = dst[e], t = etype[e];
    const float* hs = h1 + (size_t)s * 8;
    const float* w = w2 + (size_t)t * 24;   // [b][i][o] = [4][2][3]
    float* out = h2 + (size_t)d * 12;
#pragma unroll
    for (int b = 0; b < 4; b++) {
        float a0 = hs[b * 2 + 0], a1 = hs[b * 2 + 1];
        const float* wb = w + b * 6;
#pragma unroll
        for (int o = 0; o < 3; o++)
            atomicAdd(&out[b * 3 + o], a0 * wb[o] + a1 * wb[3 + o]);
    }
}

// ---------------- layer 2 node pass: h2 = relu(h2 + h1@root2 + b2) ----------------
__global__ void node2_kernel(const float* __restrict__ h1, const float* __restrict__ root2,
                             const float* __restrict__ b2, float* __restrict__ h2) {
    int n = blockIdx.x * blockDim.x + threadIdx.x;
    if (n >= NN) return;
    const float* hs = h1 + (size_t)n * 8;
    float* h = h2 + (size_t)n * 12;
    float hv[8];
#pragma unroll
    for (int i = 0; i < 8; i++) hv[i] = hs[i];
#pragma unroll
    for (int j = 0; j < 12; j++) {
        float v = h[j] + b2[j];
#pragma unroll
        for (int i = 0; i < 8; i++) v += hv[i] * root2[i * 12 + j];
        h[j] = fmaxf(v, 0.0f);
    }
}

// ---------------- layer 3 edge pass: in=12 (2 x 6), out=4 (2 x 2), mean ----------------
__global__ void edge3_kernel(const int* __restrict__ src, const int* __restrict__ dst,
                             const int* __restrict__ etype,
                             const float* __restrict__ h2, const float* __restrict__ w3,
                             const unsigned int* __restrict__ cnt,
                             float* __restrict__ h3) {
    int e = blockIdx.x * blockDim.x + threadIdx.x;
    if (e >= NE) return;
    int s = src[e], d = dst[e], t = etype[e];
    float norm = 1.0f / fmaxf((float)cnt[d * NR + t], 1.0f);
    const float* hs = h2 + (size_t)s * 12;
    const float* w = w3 + (size_t)t * 24;   // [b][i][o] = [2][6][2]
    float* out = h3 + (size_t)d * 4;
#pragma unroll
    for (int b = 0; b < 2; b++) {
        const float* wb = w + b * 12;
        float m0 = 0.0f, m1 = 0.0f;
#pragma unroll
        for (int i = 0; i < 6; i++) {
            float a = hs[b * 6 + i];
            m0 += a * wb[i * 2 + 0];
            m1 += a * wb[i * 2 + 1];
        }
        atomicAdd(&out[b * 2 + 0], m0 * norm);
        atomicAdd(&out[b * 2 + 1], m1 * norm);
    }
}

// ---------------- layer 3 node pass + log_softmax ----------------
__global__ void node3_kernel(const float* __restrict__ h2, const float* __restrict__ root3,
                             const float* __restrict__ b3, const float* __restrict__ h3,
                             float* __restrict__ out) {
    int n = blockIdx.x * blockDim.x + threadIdx.x;
    if (n >= NN) return;
    const float* hs = h2 + (size_t)n * 12;
    const float* a = h3 + (size_t)n * 4;
    float hv[12];
#pragma unroll
    for (int i = 0; i < 12; i++) hv[i] = hs[i];
    float t[4];
#pragma unroll
    for (int j = 0; j < 4; j++) {
        float v = a[j] + b3[j];
#pragma unroll
        for (int i = 0; i < 12; i++) v += hv[i] * root3[i * 4 + j];
        t[j] = v;
    }
    float m = fmaxf(fmaxf(t[0], t[1]), fmaxf(t[2], t[3]));
    float s = 0.0f;
#pragma unroll
    for (int j = 0; j < 4; j++) s += __expf(t[j] - m);
    float lse = m + __logf(s);
    float* o = out + (size_t)n * 4;
#pragma unroll
    for (int j = 0; j < 4; j++) o[j] = t[j] - lse;
}

extern "C" void kernel_launch(void* const* d_in, const int* in_sizes, int n_in,
                              void* d_out, int out_size, void* d_ws, size_t ws_size,
                              hipStream_t stream) {
    const float* x     = (const float*)d_in[0];
    const int*   ei    = (const int*)d_in[1];   // [2, E]: src = ei, dst = ei + NE
    const int*   etype = (const int*)d_in[2];
    const float* w1    = (const float*)d_in[3];
    const float* root1 = (const float*)d_in[4];
    const float* b1    = (const float*)d_in[5];
    const float* w2    = (const float*)d_in[6];
    const float* root2 = (const float*)d_in[7];
    const float* b2    = (const float*)d_in[8];
    const float* w3    = (const float*)d_in[9];
    const float* root3 = (const float*)d_in[10];
    const float* b3    = (const float*)d_in[11];
    float* out = (float*)d_out;

    const int* src = ei;
    const int* dst = ei + NE;

    // workspace layout (bytes):
    //   cnt : [NN*NR] u32   @ 0          (36,000,000)
    //   h1  : [NN*8]  f32   @ 36,000,000 ( 3,200,000)
    //   h2  : [NN*12] f32   @ 39,200,000 ( 4,800,000)
    //   h3  : [NN*4]  f32   @ 44,000,000 ( 1,600,000)  -> total 45,600,000
    char* ws = (char*)d_ws;
    unsigned int* cnt = (unsigned int*)ws;
    float* h1 = (float*)(ws + 36000000);
    float* h2 = (float*)(ws + 39200000);
    float* h3 = (float*)(ws + 44000000);

    hipMemsetAsync(d_ws, 0, 45600000, stream);

    dim3 blk(256);
    dim3 egrid((NE + 255) / 256);
    dim3 ngrid((NN + 255) / 256);

    count_kernel<<<egrid, blk, 0, stream>>>(dst, etype, cnt);
    edge1_kernel<<<egrid, blk, 0, stream>>>(src, dst, etype, x, w1, cnt, h1);
    node1_kernel<<<ngrid, blk, 0, stream>>>(x, root1, b1, h1);
    edge2_kernel<<<egrid, blk, 0, stream>>>(src, dst, etype, h1, w2, h2);
    node2_kernel<<<ngrid, blk, 0, stream>>>(h1, root2, b2, h2);
    edge3_kernel<<<egrid, blk, 0, stream>>>(src, dst, etype, h2, w3, cnt, h3);
    node3_kernel<<<ngrid, blk, 0, stream>>>(h2, root3, b3, h3, out);
}

// Round 2
// 952.957 us; speedup vs baseline: 4.2890x; 4.2890x over previous
//
#include <hip/hip_runtime.h>
#include <math.h>

#define NN 100000
#define NE 3200000
#define NR 90

typedef unsigned int u32;

// ---------------- histogram of dst degrees ----------------
__global__ void hist_kernel(const int* __restrict__ dst, u32* __restrict__ deg) {
    int e = blockIdx.x * blockDim.x + threadIdx.x;
    if (e >= NE) return;
    atomicAdd(&deg[dst[e]], 1u);
}

// ---------------- single-block exclusive scan over deg[NN] ----------------
// writes off[n] (exclusive prefix), off[NN]=NE, and re-inits deg[n]=off[n] as
// the scatter cursor.
__global__ void scan_kernel(u32* __restrict__ deg, u32* __restrict__ off) {
    __shared__ u32 part[1024];
    const int C = 98;                      // 1024*98 = 100352 >= NN
    int tid = threadIdx.x;
    int base = tid * C;
    u32 sum = 0;
    for (int i = 0; i < C; i++) {
        int idx = base + i;
        if (idx < NN) sum += deg[idx];
    }
    part[tid] = sum;
    __syncthreads();
    for (int ofs = 1; ofs < 1024; ofs <<= 1) {     // inclusive Hillis-Steele
        u32 v = (tid >= ofs) ? part[tid - ofs] : 0u;
        __syncthreads();
        part[tid] += v;
        __syncthreads();
    }
    u32 run = (tid == 0) ? 0u : part[tid - 1];
    for (int i = 0; i < C; i++) {
        int idx = base + i;
        if (idx < NN) {
            u32 d = deg[idx];
            off[idx] = run;
            deg[idx] = run;                // cursor init for scatter
            run += d;
        }
    }
    if (tid == 1023) off[NN] = run;        // == NE
}

// ---------------- scatter edges into dst-sorted record array ----------------
// rec = (src << 7) | etype   (src < 2^17, etype < 90 < 2^7)
__global__ void scatter_kernel(const int* __restrict__ src, const int* __restrict__ dst,
                               const int* __restrict__ et,
                               u32* __restrict__ cursor, u32* __restrict__ recs) {
    int e = blockIdx.x * blockDim.x + threadIdx.x;
    if (e >= NE) return;
    u32 pos = atomicAdd(&cursor[dst[e]], 1u);
    recs[pos] = ((u32)src[e] << 7) | (u32)et[e];
}

// ---------------- layer 1 fused: mean-aggr + root + bias + relu ----------------
// in=4 (2 blocks x 2), out=8 (2 x 4)
__global__ __launch_bounds__(256) void layer1_kernel(
        const u32* __restrict__ off, const u32* __restrict__ recs,
        const float* __restrict__ x, const float* __restrict__ w1,
        const float* __restrict__ root1, const float* __restrict__ b1,
        float* __restrict__ h1) {
    __shared__ unsigned char cs[256 * NR];
    int tid = threadIdx.x;
    int n = blockIdx.x * 256 + tid;
    if (n >= NN) return;
    unsigned char* mycnt = cs + tid * NR;     // private slice — no barriers needed
#pragma unroll
    for (int i = 0; i < NR; i++) mycnt[i] = 0;

    u32 k0 = off[n], k1 = off[n + 1];
    for (u32 k = k0; k < k1; k++) mycnt[recs[k] & 127u]++;

    float acc[8];
#pragma unroll
    for (int j = 0; j < 8; j++) acc[j] = 0.0f;

    for (u32 k = k0; k < k1; k++) {
        u32 rec = recs[k];
        u32 s = rec >> 7, t = rec & 127u;
        float norm = 1.0f / (float)mycnt[t];
        float4 xv = *(const float4*)(x + (size_t)s * 4);
        const float* w = w1 + (size_t)t * 16;   // [2][2][4]
#pragma unroll
        for (int o = 0; o < 4; o++) {
            acc[o]     += (xv.x * w[o]     + xv.y * w[4 + o])  * norm;
            acc[4 + o] += (xv.z * w[8 + o] + xv.w * w[12 + o]) * norm;
        }
    }
    float4 xn = *(const float4*)(x + (size_t)n * 4);
    float* h = h1 + (size_t)n * 8;
#pragma unroll
    for (int j = 0; j < 8; j++) {
        float v = acc[j] + b1[j] + xn.x * root1[j] + xn.y * root1[8 + j]
                + xn.z * root1[16 + j] + xn.w * root1[24 + j];
        h[j] = fmaxf(v, 0.0f);
    }
}

// ---------------- layer 2 fused: add-aggr + root + bias + relu ----------------
// in=8 (4 x 2), out=12 (4 x 3)
__global__ __launch_bounds__(256) void layer2_kernel(
        const u32* __restrict__ off, const u32* __restrict__ recs,
        const float* __restrict__ h1, const float* __restrict__ w2,
        const float* __restrict__ root2, const float* __restrict__ b2,
        float* __restrict__ h2) {
    int n = blockIdx.x * 256 + threadIdx.x;
    if (n >= NN) return;
    float acc[12];
#pragma unroll
    for (int j = 0; j < 12; j++) acc[j] = 0.0f;

    u32 k0 = off[n], k1 = off[n + 1];
    for (u32 k = k0; k < k1; k++) {
        u32 rec = recs[k];
        u32 s = rec >> 7, t = rec & 127u;
        const float4* hv = (const float4*)(h1 + (size_t)s * 8);
        float4 a = hv[0], b = hv[1];
        const float* w = w2 + (size_t)t * 24;   // [4][2][3]
#pragma unroll
        for (int o = 0; o < 3; o++) {
            acc[o]     += a.x * w[o]      + a.y * w[3 + o];
            acc[3 + o] += a.z * w[6 + o]  + a.w * w[9 + o];
            acc[6 + o] += b.x * w[12 + o] + b.y * w[15 + o];
            acc[9 + o] += b.z * w[18 + o] + b.w * w[21 + o];
        }
    }
    const float* hn = h1 + (size_t)n * 8;
    float hv[8];
#pragma unroll
    for (int i = 0; i < 8; i++) hv[i] = hn[i];
    float* h = h2 + (size_t)n * 12;
#pragma unroll
    for (int j = 0; j < 12; j++) {
        float v = acc[j] + b2[j];
#pragma unroll
        for (int i = 0; i < 8; i++) v += hv[i] * root2[i * 12 + j];
        h[j] = fmaxf(v, 0.0f);
    }
}

// ---------------- layer 3 fused: mean-aggr + root + bias + log_softmax ----------------
// in=12 (2 x 6), out=4 (2 x 2)
__global__ __launch_bounds__(256) void layer3_kernel(
        const u32* __restrict__ off, const u32* __restrict__ recs,
        const float* __restrict__ h2, const float* __restrict__ w3,
        const float* __restrict__ root3, const float* __restrict__ b3,
        float* __restrict__ out) {
    __shared__ unsigned char cs[256 * NR];
    int tid = threadIdx.x;
    int n = blockIdx.x * 256 + tid;
    if (n >= NN) return;
    unsigned char* mycnt = cs + tid * NR;
#pragma unroll
    for (int i = 0; i < NR; i++) mycnt[i] = 0;

    u32 k0 = off[n], k1 = off[n + 1];
    for (u32 k = k0; k < k1; k++) mycnt[recs[k] & 127u]++;

    float acc[4] = {0.0f, 0.0f, 0.0f, 0.0f};
    for (u32 k = k0; k < k1; k++) {
        u32 rec = recs[k];
        u32 s = rec >> 7, t = rec & 127u;
        float norm = 1.0f / (float)mycnt[t];
        const float* hs = h2 + (size_t)s * 12;
        const float* w = w3 + (size_t)t * 24;   // [2][6][2]
        float m0 = 0.0f, m1 = 0.0f, m2 = 0.0f, m3 = 0.0f;
#pragma unroll
        for (int i = 0; i < 6; i++) {
            float a = hs[i], b = hs[6 + i];
            m0 += a * w[i * 2];      m1 += a * w[i * 2 + 1];
            m2 += b * w[12 + i * 2]; m3 += b * w[12 + i * 2 + 1];
        }
        acc[0] += m0 * norm; acc[1] += m1 * norm;
        acc[2] += m2 * norm; acc[3] += m3 * norm;
    }
    const float* hn = h2 + (size_t)n * 12;
    float hv[12];
#pragma unroll
    for (int i = 0; i < 12; i++) hv[i] = hn[i];
    float t4[4];
#pragma unroll
    for (int j = 0; j < 4; j++) {
        float v = acc[j] + b3[j];
#pragma unroll
        for (int i = 0; i < 12; i++) v += hv[i] * root3[i * 4 + j];
        t4[j] = v;
    }
    float m = fmaxf(fmaxf(t4[0], t4[1]), fmaxf(t4[2], t4[3]));
    float s = 0.0f;
#pragma unroll
    for (int j = 0; j < 4; j++) s += __expf(t4[j] - m);
    float lse = m + __logf(s);
    float* o = out + (size_t)n * 4;
#pragma unroll
    for (int j = 0; j < 4; j++) o[j] = t4[j] - lse;
}

extern "C" void kernel_launch(void* const* d_in, const int* in_sizes, int n_in,
                              void* d_out, int out_size, void* d_ws, size_t ws_size,
                              hipStream_t stream) {
    const float* x     = (const float*)d_in[0];
    const int*   ei    = (const int*)d_in[1];   // [2, E]
    const int*   etype = (const int*)d_in[2];
    const float* w1    = (const float*)d_in[3];
    const float* root1 = (const float*)d_in[4];
    const float* b1    = (const float*)d_in[5];
    const float* w2    = (const float*)d_in[6];
    const float* root2 = (const float*)d_in[7];
    const float* b2    = (const float*)d_in[8];
    const float* w3    = (const float*)d_in[9];
    const float* root3 = (const float*)d_in[10];
    const float* b3    = (const float*)d_in[11];
    float* out = (float*)d_out;

    const int* src = ei;
    const int* dst = ei + NE;

    // workspace layout (bytes):
    //   deg/cursor : [NN]   u32 @ 0          (   400,000)
    //   off        : [NN+1] u32 @ 400,000    (   400,004)
    //   recs       : [NE]   u32 @ 800,016    (12,800,000)
    //   h1         : [NN*8] f32 @ 13,600,016 ( 3,200,000)
    //   h2         : [NN*12]f32 @ 16,800,016 ( 4,800,000)  -> total 21,600,016
    char* ws = (char*)d_ws;
    u32*   deg  = (u32*)ws;
    u32*   off  = (u32*)(ws + 400000);
    u32*   recs = (u32*)(ws + 800016);
    float* h1   = (float*)(ws + 13600016);
    float* h2   = (float*)(ws + 16800016);

    hipMemsetAsync(deg, 0, 400000, stream);

    dim3 blk(256);
    dim3 egrid((NE + 255) / 256);
    dim3 ngrid((NN + 255) / 256);

    hist_kernel<<<egrid, blk, 0, stream>>>(dst, deg);
    scan_kernel<<<1, 1024, 0, stream>>>(deg, off);
    scatter_kernel<<<egrid, blk, 0, stream>>>(src, dst, etype, deg, recs);
    layer1_kernel<<<ngrid, blk, 0, stream>>>(off, recs, x, w1, root1, b1, h1);
    layer2_kernel<<<ngrid, blk, 0, stream>>>(off, recs, h1, w2, root2, b2, h2);
    layer3_kernel<<<ngrid, blk, 0, stream>>>(off, recs, h2, w3, root3, b3, out);
}

// Round 3
// 757.614 us; speedup vs baseline: 5.3949x; 1.2578x over previous
//
#include <hip/hip_runtime.h>
#include <math.h>

#define NN 100000
#define NE 3200000
#define NR 90
#define NB 391          // ceil(NN/256) blocks for node-grid

typedef unsigned int u32;

// ---------------- histogram of dst degrees ----------------
__global__ void hist_kernel(const int* __restrict__ dst, u32* __restrict__ deg) {
    int e = blockIdx.x * blockDim.x + threadIdx.x;
    if (e >= NE) return;
    atomicAdd(&deg[dst[e]], 1u);
}

// ---------------- scan phase 1: per-block partial sums ----------------
__global__ __launch_bounds__(256) void partial_kernel(const u32* __restrict__ deg,
                                                      u32* __restrict__ bsum) {
    __shared__ u32 sh[256];
    int tid = threadIdx.x;
    int n = blockIdx.x * 256 + tid;
    sh[tid] = (n < NN) ? deg[n] : 0u;
    __syncthreads();
#pragma unroll
    for (int s = 128; s > 0; s >>= 1) {
        if (tid < s) sh[tid] += sh[tid + s];
        __syncthreads();
    }
    if (tid == 0) bsum[blockIdx.x] = sh[0];
}

// ---------------- scan phase 2: exclusive scan of NB block sums (1 block) ----------------
__global__ __launch_bounds__(512) void scanb_kernel(u32* __restrict__ bsum) {
    __shared__ u32 sh[512];
    int tid = threadIdx.x;
    sh[tid] = (tid < NB) ? bsum[tid] : 0u;
    __syncthreads();
#pragma unroll
    for (int ofs = 1; ofs < 512; ofs <<= 1) {
        u32 v = (tid >= ofs) ? sh[tid - ofs] : 0u;
        __syncthreads();
        sh[tid] += v;
        __syncthreads();
    }
    u32 excl = (tid == 0) ? 0u : sh[tid - 1];
    if (tid < NB) bsum[tid] = excl;
}

// ---------------- scan phase 3: block-local scan + add-back; writes off & cursor ----------------
__global__ __launch_bounds__(256) void offsets_kernel(u32* __restrict__ deg,
                                                      const u32* __restrict__ boff,
                                                      u32* __restrict__ off) {
    __shared__ u32 sh[256];
    int tid = threadIdx.x;
    int n = blockIdx.x * 256 + tid;
    u32 v = (n < NN) ? deg[n] : 0u;
    sh[tid] = v;
    __syncthreads();
#pragma unroll
    for (int ofs = 1; ofs < 256; ofs <<= 1) {
        u32 t = (tid >= ofs) ? sh[tid - ofs] : 0u;
        __syncthreads();
        sh[tid] += t;
        __syncthreads();
    }
    u32 excl = (tid == 0) ? 0u : sh[tid - 1];
    u32 o = boff[blockIdx.x] + excl;
    if (n < NN) { off[n] = o; deg[n] = o; }   // deg becomes the scatter cursor
    if (n == 0) off[NN] = NE;
}

// ---------------- scatter edges into dst-sorted record array ----------------
// rec = (src << 7) | etype   (src < 2^17, etype < 90 < 2^7)
__global__ void scatter_kernel(const int* __restrict__ src, const int* __restrict__ dst,
                               const int* __restrict__ et,
                               u32* __restrict__ cursor, u32* __restrict__ recs) {
    int e = blockIdx.x * blockDim.x + threadIdx.x;
    if (e >= NE) return;
    u32 pos = atomicAdd(&cursor[dst[e]], 1u);
    recs[pos] = ((u32)src[e] << 7) | (u32)et[e];
}

// ---------------- per-edge mean-normalization weights (shared by layers 1 & 3) ----------------
__global__ __launch_bounds__(256) void norm_kernel(const u32* __restrict__ off,
                                                   const u32* __restrict__ recs,
                                                   float* __restrict__ normw) {
    __shared__ unsigned char cs[256 * NR];
    int tid = threadIdx.x;
    int n = blockIdx.x * 256 + tid;
    if (n >= NN) return;
    unsigned char* mycnt = cs + tid * NR;     // private slice — no barriers needed
#pragma unroll
    for (int i = 0; i < NR; i++) mycnt[i] = 0;
    u32 k0 = off[n], k1 = off[n + 1];
    for (u32 k = k0; k < k1; k++) mycnt[recs[k] & 127u]++;
    for (u32 k = k0; k < k1; k++) normw[k] = 1.0f / (float)mycnt[recs[k] & 127u];
}

// ---------------- layer 1 fused: mean-aggr + root + bias + relu ----------------
// in=4 (2 blocks x 2), out=8 (2 x 4)
__global__ __launch_bounds__(256) void layer1_kernel(
        const u32* __restrict__ off, const u32* __restrict__ recs,
        const float* __restrict__ normw,
        const float* __restrict__ x, const float* __restrict__ w1,
        const float* __restrict__ root1, const float* __restrict__ b1,
        float* __restrict__ h1) {
    int n = blockIdx.x * 256 + threadIdx.x;
    if (n >= NN) return;
    float acc[8];
#pragma unroll
    for (int j = 0; j < 8; j++) acc[j] = 0.0f;

    u32 k0 = off[n], k1 = off[n + 1];
    for (u32 k = k0; k < k1; k++) {
        u32 rec = recs[k];
        u32 s = rec >> 7, t = rec & 127u;
        float norm = normw[k];
        float4 xv = *(const float4*)(x + (size_t)s * 4);
        const float* w = w1 + (size_t)t * 16;   // [2][2][4]
#pragma unroll
        for (int o = 0; o < 4; o++) {
            acc[o]     += (xv.x * w[o]     + xv.y * w[4 + o])  * norm;
            acc[4 + o] += (xv.z * w[8 + o] + xv.w * w[12 + o]) * norm;
        }
    }
    float4 xn = *(const float4*)(x + (size_t)n * 4);
    float* h = h1 + (size_t)n * 8;
#pragma unroll
    for (int j = 0; j < 8; j++) {
        float v = acc[j] + b1[j] + xn.x * root1[j] + xn.y * root1[8 + j]
                + xn.z * root1[16 + j] + xn.w * root1[24 + j];
        h[j] = fmaxf(v, 0.0f);
    }
}

// ---------------- layer 2 fused: add-aggr + root + bias + relu ----------------
// in=8 (4 x 2), out=12 (4 x 3)
__global__ __launch_bounds__(256) void layer2_kernel(
        const u32* __restrict__ off, const u32* __restrict__ recs,
        const float* __restrict__ h1, const float* __restrict__ w2,
        const float* __restrict__ root2, const float* __restrict__ b2,
        float* __restrict__ h2) {
    int n = blockIdx.x * 256 + threadIdx.x;
    if (n >= NN) return;
    float acc[12];
#pragma unroll
    for (int j = 0; j < 12; j++) acc[j] = 0.0f;

    u32 k0 = off[n], k1 = off[n + 1];
    for (u32 k = k0; k < k1; k++) {
        u32 rec = recs[k];
        u32 s = rec >> 7, t = rec & 127u;
        const float4* hv = (const float4*)(h1 + (size_t)s * 8);
        float4 a = hv[0], b = hv[1];
        const float* w = w2 + (size_t)t * 24;   // [4][2][3]
#pragma unroll
        for (int o = 0; o < 3; o++) {
            acc[o]     += a.x * w[o]      + a.y * w[3 + o];
            acc[3 + o] += a.z * w[6 + o]  + a.w * w[9 + o];
            acc[6 + o] += b.x * w[12 + o] + b.y * w[15 + o];
            acc[9 + o] += b.z * w[18 + o] + b.w * w[21 + o];
        }
    }
    const float* hn = h1 + (size_t)n * 8;
    float hv[8];
#pragma unroll
    for (int i = 0; i < 8; i++) hv[i] = hn[i];
    float* h = h2 + (size_t)n * 12;
#pragma unroll
    for (int j = 0; j < 12; j++) {
        float v = acc[j] + b2[j];
#pragma unroll
        for (int i = 0; i < 8; i++) v += hv[i] * root2[i * 12 + j];
        h[j] = fmaxf(v, 0.0f);
    }
}

// ---------------- layer 3 fused: mean-aggr + root + bias + log_softmax ----------------
// in=12 (2 x 6), out=4 (2 x 2)
__global__ __launch_bounds__(256) void layer3_kernel(
        const u32* __restrict__ off, const u32* __restrict__ recs,
        const float* __restrict__ normw,
        const float* __restrict__ h2, const float* __restrict__ w3,
        const float* __restrict__ root3, const float* __restrict__ b3,
        float* __restrict__ out) {
    int n = blockIdx.x * 256 + threadIdx.x;
    if (n >= NN) return;
    float acc[4] = {0.0f, 0.0f, 0.0f, 0.0f};
    u32 k0 = off[n], k1 = off[n + 1];
    for (u32 k = k0; k < k1; k++) {
        u32 rec = recs[k];
        u32 s = rec >> 7, t = rec & 127u;
        float norm = normw[k];
        const float* hs = h2 + (size_t)s * 12;
        const float* w = w3 + (size_t)t * 24;   // [2][6][2]
        float m0 = 0.0f, m1 = 0.0f, m2 = 0.0f, m3 = 0.0f;
#pragma unroll
        for (int i = 0; i < 6; i++) {
            float a = hs[i], b = hs[6 + i];
            m0 += a * w[i * 2];      m1 += a * w[i * 2 + 1];
            m2 += b * w[12 + i * 2]; m3 += b * w[12 + i * 2 + 1];
        }
        acc[0] += m0 * norm; acc[1] += m1 * norm;
        acc[2] += m2 * norm; acc[3] += m3 * norm;
    }
    const float* hn = h2 + (size_t)n * 12;
    float hv[12];
#pragma unroll
    for (int i = 0; i < 12; i++) hv[i] = hn[i];
    float t4[4];
#pragma unroll
    for (int j = 0; j < 4; j++) {
        float v = acc[j] + b3[j];
#pragma unroll
        for (int i = 0; i < 12; i++) v += hv[i] * root3[i * 4 + j];
        t4[j] = v;
    }
    float m = fmaxf(fmaxf(t4[0], t4[1]), fmaxf(t4[2], t4[3]));
    float s = 0.0f;
#pragma unroll
    for (int j = 0; j < 4; j++) s += __expf(t4[j] - m);
    float lse = m + __logf(s);
    float* o = out + (size_t)n * 4;
#pragma unroll
    for (int j = 0; j < 4; j++) o[j] = t4[j] - lse;
}

extern "C" void kernel_launch(void* const* d_in, const int* in_sizes, int n_in,
                              void* d_out, int out_size, void* d_ws, size_t ws_size,
                              hipStream_t stream) {
    const float* x     = (const float*)d_in[0];
    const int*   ei    = (const int*)d_in[1];   // [2, E]
    const int*   etype = (const int*)d_in[2];
    const float* w1    = (const float*)d_in[3];
    const float* root1 = (const float*)d_in[4];
    const float* b1    = (const float*)d_in[5];
    const float* w2    = (const float*)d_in[6];
    const float* root2 = (const float*)d_in[7];
    const float* b2    = (const float*)d_in[8];
    const float* w3    = (const float*)d_in[9];
    const float* root3 = (const float*)d_in[10];
    const float* b3    = (const float*)d_in[11];
    float* out = (float*)d_out;

    const int* src = ei;
    const int* dst = ei + NE;

    // workspace layout (bytes):
    //   deg/cursor : [NN]   u32 @ 0           (   400,000)
    //   off        : [NN+1] u32 @ 400,000     (   400,004 -> pad 400,016)
    //   bsum/boff  : [512]  u32 @ 800,016     (     2,048)
    //   recs       : [NE]   u32 @ 802,064     (12,800,000)
    //   normw      : [NE]   f32 @ 13,602,064  (12,800,000)
    //   h1         : [NN*8] f32 @ 26,402,064  ( 3,200,000)
    //   h2         : [NN*12]f32 @ 29,602,064  ( 4,800,000) -> total 34,402,064
    char* ws = (char*)d_ws;
    u32*   deg   = (u32*)ws;
    u32*   off   = (u32*)(ws + 400000);
    u32*   bsum  = (u32*)(ws + 800016);
    u32*   recs  = (u32*)(ws + 802064);
    float* normw = (float*)(ws + 13602064);
    float* h1    = (float*)(ws + 26402064);
    float* h2    = (float*)(ws + 29602064);

    hipMemsetAsync(deg, 0, 400000, stream);

    dim3 blk(256);
    dim3 egrid((NE + 255) / 256);
    dim3 ngrid(NB);

    hist_kernel<<<egrid, blk, 0, stream>>>(dst, deg);
    partial_kernel<<<ngrid, blk, 0, stream>>>(deg, bsum);
    scanb_kernel<<<1, 512, 0, stream>>>(bsum);
    offsets_kernel<<<ngrid, blk, 0, stream>>>(deg, bsum, off);
    scatter_kernel<<<egrid, blk, 0, stream>>>(src, dst, etype, deg, recs);
    norm_kernel<<<ngrid, blk, 0, stream>>>(off, recs, normw);
    layer1_kernel<<<ngrid, blk, 0, stream>>>(off, recs, normw, x, w1, root1, b1, h1);
    layer2_kernel<<<ngrid, blk, 0, stream>>>(off, recs, h1, w2, root2, b2, h2);
    layer3_kernel<<<ngrid, blk, 0, stream>>>(off, recs, normw, h2, w3, root3, b3, out);
}

// Round 5
// 470.168 us; speedup vs baseline: 8.6932x; 1.6114x over previous
//
#include <hip/hip_runtime.h>
#include <math.h>

#define NN 100000
#define NE 3200000
#define NR 90
#define NB 391          // ceil(NN/256): node-grid blocks, coarse buckets (dst>>8)
#define CH 8192         // edges per block in partition passes

typedef unsigned int u32;

// ---------------- coarse histogram: bucket = dst >> 8 ----------------
__global__ __launch_bounds__(256) void coarse_count_kernel(const int* __restrict__ dst,
                                                           u32* __restrict__ ccnt) {
    __shared__ u32 bh[NB];
    int tid = threadIdx.x;
    for (int b = tid; b < NB; b += 256) bh[b] = 0;
    __syncthreads();
    int c0 = blockIdx.x * CH;
    int c1 = c0 + CH; if (c1 > NE) c1 = NE;
    for (int e = c0 + tid; e < c1; e += 256)
        atomicAdd(&bh[(u32)dst[e] >> 8], 1u);
    __syncthreads();
    for (int b = tid; b < NB; b += 256) {
        u32 c = bh[b];
        if (c) atomicAdd(&ccnt[b], c);
    }
}

// ---------------- exclusive scan of NB coarse counts (1 block) ----------------
__global__ __launch_bounds__(512) void scan_coff_kernel(const u32* __restrict__ ccnt,
                                                        u32* __restrict__ coff,
                                                        u32* __restrict__ ccursor) {
    __shared__ u32 sh[512];
    int tid = threadIdx.x;
    sh[tid] = (tid < NB) ? ccnt[tid] : 0u;
    __syncthreads();
#pragma unroll
    for (int ofs = 1; ofs < 512; ofs <<= 1) {
        u32 v = (tid >= ofs) ? sh[tid - ofs] : 0u;
        __syncthreads();
        sh[tid] += v;
        __syncthreads();
    }
    u32 excl = (tid == 0) ? 0u : sh[tid - 1];
    if (tid < NB) { coff[tid] = excl; ccursor[tid] = excl; }
    if (tid == 0) coff[NB] = NE;
}

// ---------------- pass 1: coarse partition into bucket-contiguous tmp ----------------
// tmp entry: (dst&255)<<24 | src<<7 | et   (8+17+7 = 32 bits; bucket implied by position)
__global__ __launch_bounds__(256) void pass1_kernel(const int* __restrict__ src,
                                                    const int* __restrict__ dst,
                                                    const int* __restrict__ et,
                                                    u32* __restrict__ ccursor,
                                                    u32* __restrict__ tmp) {
    __shared__ u32 bh[NB];
    int tid = threadIdx.x;
    for (int b = tid; b < NB; b += 256) bh[b] = 0;
    __syncthreads();
    int c0 = blockIdx.x * CH;
    int c1 = c0 + CH; if (c1 > NE) c1 = NE;
    // local bucket histogram
    for (int e = c0 + tid; e < c1; e += 256)
        atomicAdd(&bh[(u32)dst[e] >> 8], 1u);
    __syncthreads();
    // reserve one contiguous run per non-empty bucket; bh becomes global cursor
    for (int b = tid; b < NB; b += 256) {
        u32 c = bh[b];
        if (c) bh[b] = atomicAdd(&ccursor[b], c);
    }
    __syncthreads();
    // scatter into reserved runs (writes confined to ~CH*4B of bucket regions)
    for (int e = c0 + tid; e < c1; e += 256) {
        u32 d = (u32)dst[e];
        u32 pos = atomicAdd(&bh[d >> 8], 1u);
        tmp[pos] = ((d & 255u) << 24) | ((u32)src[e] << 7) | (u32)et[e];
    }
}

// ---------------- pass 2: per-bucket fine sort + off[] + normw[] ----------------
// one block per bucket; bucket covers nodes [b*256, b*256+256)
// normw ALIASES tmp (block consumes its tmp run before overwriting) — no __restrict__.
__global__ __launch_bounds__(256) void pass2_kernel(const u32* tmp,
                                                    const u32* __restrict__ coff,
                                                    u32* __restrict__ off,
                                                    u32* __restrict__ recs,
                                                    float* normw) {
    __shared__ u32 dh[256];          // per-node degree
    __shared__ u32 lcur[256];        // per-node cursor (relative)
    __shared__ u32 cnt32[256 * 23];  // per-(node,rel) u8 counts packed 4/word
    int tid = threadIdx.x;
    int b = blockIdx.x;
    u32 r0 = coff[b], r1 = coff[b + 1];

    dh[tid] = 0;
#pragma unroll
    for (int i = 0; i < 23; i++) cnt32[tid * 23 + i] = 0;
    __syncthreads();

    // A: per-node degrees
    for (u32 k = r0 + tid; k < r1; k += 256)
        atomicAdd(&dh[tmp[k] >> 24], 1u);
    __syncthreads();

    // B: inclusive scan of dh
    __shared__ u32 sh[256];
    sh[tid] = dh[tid];
    __syncthreads();
#pragma unroll
    for (int ofs = 1; ofs < 256; ofs <<= 1) {
        u32 v = (tid >= ofs) ? sh[tid - ofs] : 0u;
        __syncthreads();
        sh[tid] += v;
        __syncthreads();
    }
    u32 excl = (tid == 0) ? 0u : sh[tid - 1];
    int n = b * 256 + tid;
    if (n < NN) off[n] = r0 + excl;
    if (b == NB - 1 && tid == 0) off[NN] = NE;
    lcur[tid] = excl;
    __syncthreads();

    // C: fine scatter within this bucket's 32KB recs window + rel counts
    for (u32 k = r0 + tid; k < r1; k += 256) {
        u32 v = tmp[k];
        u32 ln = v >> 24;
        u32 rec = v & 0xFFFFFFu;          // src<<7 | et
        u32 rel = v & 127u;
        u32 pos = atomicAdd(&lcur[ln], 1u);
        recs[r0 + pos] = rec;
        atomicAdd(&cnt32[ln * 23 + (rel >> 2)], 1u << ((rel & 3u) * 8u));
    }
    __syncthreads();

    // D: per-edge mean weights (normw aliases tmp; tmp fully consumed above)
    u32 start = (tid == 0) ? 0u : lcur[tid - 1];
    u32 end = lcur[tid];
    if (n < NN) {
        for (u32 j = start; j < end; j++) {
            u32 rel = recs[r0 + j] & 127u;
            u32 c = (cnt32[tid * 23 + (rel >> 2)] >> ((rel & 3u) * 8u)) & 255u;
            normw[r0 + j] = 1.0f / (float)c;
        }
    }
}

// ---------------- layer 1 fused: mean-aggr + root + bias + relu ----------------
__global__ __launch_bounds__(256) void layer1_kernel(
        const u32* __restrict__ off, const u32* __restrict__ recs,
        const float* __restrict__ normw,
        const float* __restrict__ x, const float* __restrict__ w1,
        const float* __restrict__ root1, const float* __restrict__ b1,
        float* __restrict__ h1) {
    int n = blockIdx.x * 256 + threadIdx.x;
    if (n >= NN) return;
    float acc[8];
#pragma unroll
    for (int j = 0; j < 8; j++) acc[j] = 0.0f;

    u32 k0 = off[n], k1 = off[n + 1];
    for (u32 k = k0; k < k1; k++) {
        u32 rec = recs[k];
        u32 s = rec >> 7, t = rec & 127u;
        float norm = normw[k];
        float4 xv = *(const float4*)(x + (size_t)s * 4);
        const float* w = w1 + (size_t)t * 16;   // [2][2][4]
#pragma unroll
        for (int o = 0; o < 4; o++) {
            acc[o]     += (xv.x * w[o]     + xv.y * w[4 + o])  * norm;
            acc[4 + o] += (xv.z * w[8 + o] + xv.w * w[12 + o]) * norm;
        }
    }
    float4 xn = *(const float4*)(x + (size_t)n * 4);
    float* h = h1 + (size_t)n * 8;
#pragma unroll
    for (int j = 0; j < 8; j++) {
        float v = acc[j] + b1[j] + xn.x * root1[j] + xn.y * root1[8 + j]
                + xn.z * root1[16 + j] + xn.w * root1[24 + j];
        h[j] = fmaxf(v, 0.0f);
    }
}

// ---------------- layer 2 fused: add-aggr + root + bias + relu ----------------
__global__ __launch_bounds__(256) void layer2_kernel(
        const u32* __restrict__ off, const u32* __restrict__ recs,
        const float* __restrict__ h1, const float* __restrict__ w2,
        const float* __restrict__ root2, const float* __restrict__ b2,
        float* __restrict__ h2) {
    int n = blockIdx.x * 256 + threadIdx.x;
    if (n >= NN) return;
    float acc[12];
#pragma unroll
    for (int j = 0; j < 12; j++) acc[j] = 0.0f;

    u32 k0 = off[n], k1 = off[n + 1];
    for (u32 k = k0; k < k1; k++) {
        u32 rec = recs[k];
        u32 s = rec >> 7, t = rec & 127u;
        const float4* hv = (const float4*)(h1 + (size_t)s * 8);
        float4 a = hv[0], b = hv[1];
        const float* w = w2 + (size_t)t * 24;   // [4][2][3]
#pragma unroll
        for (int o = 0; o < 3; o++) {
            acc[o]     += a.x * w[o]      + a.y * w[3 + o];
            acc[3 + o] += a.z * w[6 + o]  + a.w * w[9 + o];
            acc[6 + o] += b.x * w[12 + o] + b.y * w[15 + o];
            acc[9 + o] += b.z * w[18 + o] + b.w * w[21 + o];
        }
    }
    const float* hn = h1 + (size_t)n * 8;
    float hv[8];
#pragma unroll
    for (int i = 0; i < 8; i++) hv[i] = hn[i];
    float* h = h2 + (size_t)n * 12;
#pragma unroll
    for (int j = 0; j < 12; j++) {
        float v = acc[j] + b2[j];
#pragma unroll
        for (int i = 0; i < 8; i++) v += hv[i] * root2[i * 12 + j];
        h[j] = fmaxf(v, 0.0f);
    }
}

// ---------------- layer 3 fused: mean-aggr + root + bias + log_softmax ----------------
__global__ __launch_bounds__(256) void layer3_kernel(
        const u32* __restrict__ off, const u32* __restrict__ recs,
        const float* __restrict__ normw,
        const float* __restrict__ h2, const float* __restrict__ w3,
        const float* __restrict__ root3, const float* __restrict__ b3,
        float* __restrict__ out) {
    int n = blockIdx.x * 256 + threadIdx.x;
    if (n >= NN) return;
    float acc[4] = {0.0f, 0.0f, 0.0f, 0.0f};
    u32 k0 = off[n], k1 = off[n + 1];
    for (u32 k = k0; k < k1; k++) {
        u32 rec = recs[k];
        u32 s = rec >> 7, t = rec & 127u;
        float norm = normw[k];
        const float* hs = h2 + (size_t)s * 12;
        const float* w = w3 + (size_t)t * 24;   // [2][6][2]
        float m0 = 0.0f, m1 = 0.0f, m2 = 0.0f, m3 = 0.0f;
#pragma unroll
        for (int i = 0; i < 6; i++) {
            float a = hs[i], b = hs[6 + i];
            m0 += a * w[i * 2];      m1 += a * w[i * 2 + 1];
            m2 += b * w[12 + i * 2]; m3 += b * w[12 + i * 2 + 1];
        }
        acc[0] += m0 * norm; acc[1] += m1 * norm;
        acc[2] += m2 * norm; acc[3] += m3 * norm;
    }
    const float* hn = h2 + (size_t)n * 12;
    float hv[12];
#pragma unroll
    for (int i = 0; i < 12; i++) hv[i] = hn[i];
    float t4[4];
#pragma unroll
    for (int j = 0; j < 4; j++) {
        float v = acc[j] + b3[j];
#pragma unroll
        for (int i = 0; i < 12; i++) v += hv[i] * root3[i * 4 + j];
        t4[j] = v;
    }
    float m = fmaxf(fmaxf(t4[0], t4[1]), fmaxf(t4[2], t4[3]));
    float s = 0.0f;
#pragma unroll
    for (int j = 0; j < 4; j++) s += __expf(t4[j] - m);
    float lse = m + __logf(s);
    float* o = out + (size_t)n * 4;
#pragma unroll
    for (int j = 0; j < 4; j++) o[j] = t4[j] - lse;
}

extern "C" void kernel_launch(void* const* d_in, const int* in_sizes, int n_in,
                              void* d_out, int out_size, void* d_ws, size_t ws_size,
                              hipStream_t stream) {
    const float* x     = (const float*)d_in[0];
    const int*   ei    = (const int*)d_in[1];   // [2, E]
    const int*   etype = (const int*)d_in[2];
    const float* w1    = (const float*)d_in[3];
    const float* root1 = (const float*)d_in[4];
    const float* b1    = (const float*)d_in[5];
    const float* w2    = (const float*)d_in[6];
    const float* root2 = (const float*)d_in[7];
    const float* b2    = (const float*)d_in[8];
    const float* w3    = (const float*)d_in[9];
    const float* root3 = (const float*)d_in[10];
    const float* b3    = (const float*)d_in[11];
    float* out = (float*)d_out;

    const int* src = ei;
    const int* dst = ei + NE;

    // workspace layout (bytes) — FIXED: off ends at 404,804; tmp moved past it.
    //   ccnt    : [NB]    u32 @ 0           (1,564 -> pad 1,600)
    //   ccursor : [NB]    u32 @ 1,600       (1,564 -> pad 3,200)
    //   coff    : [NB+1]  u32 @ 3,200       (1,568 -> pad 4,800)
    //   off     : [NN+1]  u32 @ 4,800       (400,004 -> ends 404,804, pad 406,400)
    //   tmp / normw : [NE] u32/f32 @ 406,400   (12,800,000)   (aliased)
    //   recs    : [NE]    u32 @ 13,206,400  (12,800,000)
    //   h1      : [NN*8]  f32 @ 26,006,400  ( 3,200,000)
    //   h2      : [NN*12] f32 @ 29,206,400  ( 4,800,000)  -> total 34,006,400
    char* ws = (char*)d_ws;
    u32*   ccnt    = (u32*)ws;
    u32*   ccursor = (u32*)(ws + 1600);
    u32*   coff    = (u32*)(ws + 3200);
    u32*   off     = (u32*)(ws + 4800);
    u32*   tmp     = (u32*)(ws + 406400);
    float* normw   = (float*)(ws + 406400);   // aliases tmp (consumed in pass2)
    u32*   recs    = (u32*)(ws + 13206400);
    float* h1      = (float*)(ws + 26006400);
    float* h2      = (float*)(ws + 29206400);

    hipMemsetAsync(ccnt, 0, NB * sizeof(u32), stream);

    dim3 blk(256);
    dim3 pgrid((NE + CH - 1) / CH);   // 391
    dim3 ngrid(NB);                   // 391

    coarse_count_kernel<<<pgrid, blk, 0, stream>>>(dst, ccnt);
    scan_coff_kernel<<<1, 512, 0, stream>>>(ccnt, coff, ccursor);
    pass1_kernel<<<pgrid, blk, 0, stream>>>(src, dst, etype, ccursor, tmp);
    pass2_kernel<<<ngrid, blk, 0, stream>>>(tmp, coff, off, recs, normw);
    layer1_kernel<<<ngrid, blk, 0, stream>>>(off, recs, normw, x, w1, root1, b1, h1);
    layer2_kernel<<<ngrid, blk, 0, stream>>>(off, recs, h1, w2, root2, b2, h2);
    layer3_kernel<<<ngrid, blk, 0, stream>>>(off, recs, normw, h2, w3, root3, b3, out);
}

// Round 6
// 331.046 us; speedup vs baseline: 12.3465x; 1.4202x over previous
//
#include <hip/hip_runtime.h>
#include <math.h>

#define NN 100000
#define NE 3200000
#define NR 90
#define NB 391          // ceil(NN/256): node-grid blocks, coarse buckets (dst>>8)
#define CH 8192         // edges per block in partition passes

typedef unsigned int u32;

__device__ inline u32 pack2(float a, float b) {       // bf16(a) in lo16, bf16(b) in hi16 (RNE)
    u32 ua = __float_as_uint(a); ua += 0x7FFFu + ((ua >> 16) & 1u);
    u32 ub = __float_as_uint(b); ub += 0x7FFFu + ((ub >> 16) & 1u);
    return (ua >> 16) | (ub & 0xFFFF0000u);
}
__device__ inline float unlo(u32 w) { return __uint_as_float(w << 16); }
__device__ inline float unhi(u32 w) { return __uint_as_float(w & 0xFFFF0000u); }

// ---------------- coarse histogram: bucket = dst >> 8 ----------------
__global__ __launch_bounds__(256) void coarse_count_kernel(const int* __restrict__ dst,
                                                           u32* __restrict__ ccnt) {
    __shared__ u32 bh[NB];
    int tid = threadIdx.x;
    for (int b = tid; b < NB; b += 256) bh[b] = 0;
    __syncthreads();
    int c0 = blockIdx.x * CH;
    int c1 = c0 + CH; if (c1 > NE) c1 = NE;
    for (int e = c0 + tid; e < c1; e += 256)
        atomicAdd(&bh[(u32)dst[e] >> 8], 1u);
    __syncthreads();
    for (int b = tid; b < NB; b += 256) {
        u32 c = bh[b];
        if (c) atomicAdd(&ccnt[b], c);
    }
}

// ---------------- exclusive scan of NB coarse counts (1 block) ----------------
__global__ __launch_bounds__(512) void scan_coff_kernel(const u32* __restrict__ ccnt,
                                                        u32* __restrict__ coff,
                                                        u32* __restrict__ ccursor) {
    __shared__ u32 sh[512];
    int tid = threadIdx.x;
    sh[tid] = (tid < NB) ? ccnt[tid] : 0u;
    __syncthreads();
#pragma unroll
    for (int ofs = 1; ofs < 512; ofs <<= 1) {
        u32 v = (tid >= ofs) ? sh[tid - ofs] : 0u;
        __syncthreads();
        sh[tid] += v;
        __syncthreads();
    }
    u32 excl = (tid == 0) ? 0u : sh[tid - 1];
    if (tid < NB) { coff[tid] = excl; ccursor[tid] = excl; }
    if (tid == 0) coff[NB] = NE;
}

// ---------------- pass 1: coarse partition into bucket-contiguous tmp ----------------
// tmp entry: (dst&255)<<24 | src<<7 | et
__global__ __launch_bounds__(256) void pass1_kernel(const int* __restrict__ src,
                                                    const int* __restrict__ dst,
                                                    const int* __restrict__ et,
                                                    u32* __restrict__ ccursor,
                                                    u32* __restrict__ tmp) {
    __shared__ u32 bh[NB];
    int tid = threadIdx.x;
    for (int b = tid; b < NB; b += 256) bh[b] = 0;
    __syncthreads();
    int c0 = blockIdx.x * CH;
    int c1 = c0 + CH; if (c1 > NE) c1 = NE;
    for (int e = c0 + tid; e < c1; e += 256)
        atomicAdd(&bh[(u32)dst[e] >> 8], 1u);
    __syncthreads();
    for (int b = tid; b < NB; b += 256) {
        u32 c = bh[b];
        if (c) bh[b] = atomicAdd(&ccursor[b], c);
    }
    __syncthreads();
    for (int e = c0 + tid; e < c1; e += 256) {
        u32 d = (u32)dst[e];
        u32 pos = atomicAdd(&bh[d >> 8], 1u);
        tmp[pos] = ((d & 255u) << 24) | ((u32)src[e] << 7) | (u32)et[e];
    }
}

// ---------------- pass 2: per-bucket fine sort; recs gets cnt<<24 | src<<7 | et ----------------
// also packs x -> xb (bf16x4) for layer1's gathers.
__global__ __launch_bounds__(256) void pass2_kernel(const u32* __restrict__ tmp,
                                                    const u32* __restrict__ coff,
                                                    u32* __restrict__ off,
                                                    u32* __restrict__ recs,
                                                    const float* __restrict__ x,
                                                    uint2* __restrict__ xb) {
    __shared__ u32 dh[256];          // per-node degree
    __shared__ u32 lcur[256];        // per-node cursor (relative)
    __shared__ u32 cnt32[256 * 23];  // per-(node,rel) u8 counts packed 4/word
    __shared__ u32 sh[256];
    int tid = threadIdx.x;
    int b = blockIdx.x;
    u32 r0 = coff[b], r1 = coff[b + 1];

    dh[tid] = 0;
#pragma unroll
    for (int i = 0; i < 23; i++) cnt32[tid * 23 + i] = 0;
    __syncthreads();

    // A: per-node degrees
    for (u32 k = r0 + tid; k < r1; k += 256)
        atomicAdd(&dh[tmp[k] >> 24], 1u);
    __syncthreads();

    // B: inclusive scan of dh
    sh[tid] = dh[tid];
    __syncthreads();
#pragma unroll
    for (int ofs = 1; ofs < 256; ofs <<= 1) {
        u32 v = (tid >= ofs) ? sh[tid - ofs] : 0u;
        __syncthreads();
        sh[tid] += v;
        __syncthreads();
    }
    u32 excl = (tid == 0) ? 0u : sh[tid - 1];
    int n = b * 256 + tid;
    if (n < NN) off[n] = r0 + excl;
    if (b == NB - 1 && tid == 0) off[NN] = NE;
    lcur[tid] = excl;
    __syncthreads();

    // C: fine scatter into this bucket's recs window + per-(node,rel) counts
    for (u32 k = r0 + tid; k < r1; k += 256) {
        u32 v = tmp[k];
        u32 ln = v >> 24;
        u32 rec = v & 0xFFFFFFu;          // src<<7 | et
        u32 rel = v & 127u;
        u32 pos = atomicAdd(&lcur[ln], 1u);
        recs[r0 + pos] = rec;
        atomicAdd(&cnt32[ln * 23 + (rel >> 2)], 1u << ((rel & 3u) * 8u));
    }
    __syncthreads();

    // D: embed per-(node,rel) count into the top byte of each rec
    u32 start = (tid == 0) ? 0u : lcur[tid - 1];
    u32 end = lcur[tid];
    if (n < NN) {
        for (u32 j = start; j < end; j++) {
            u32 rel = recs[r0 + j] & 127u;
            u32 c = (cnt32[tid * 23 + (rel >> 2)] >> ((rel & 3u) * 8u)) & 255u;
            recs[r0 + j] |= c << 24;
        }
        // pack x for layer1 gathers
        float4 xv = *(const float4*)(x + (size_t)n * 4);
        xb[n] = make_uint2(pack2(xv.x, xv.y), pack2(xv.z, xv.w));
    }
}

// ---------------- layer 1: mean-aggr + root + bias + relu  (4 lanes/node) ----------------
// in=4 (2x2), out=8 (2x4). writes h1f (fp32) + h1b (bf16x8, 16B)
__global__ __launch_bounds__(256) void layer1_kernel(
        const u32* __restrict__ off, const u32* __restrict__ recs,
        const uint2* __restrict__ xb,
        const float* __restrict__ x, const float* __restrict__ w1,
        const float* __restrict__ root1, const float* __restrict__ b1,
        float* __restrict__ h1f, uint4* __restrict__ h1b) {
    int gid = blockIdx.x * 256 + threadIdx.x;
    int n = gid >> 2, r = gid & 3;
    if (n >= NN) return;
    float acc[8];
#pragma unroll
    for (int j = 0; j < 8; j++) acc[j] = 0.0f;

    u32 k0 = off[n], k1 = off[n + 1];
    for (u32 k = k0 + r; k < k1; k += 4) {
        u32 rec = recs[k];
        u32 t = rec & 127u, s = (rec >> 7) & 0x1FFFFu;
        float norm = 1.0f / (float)(rec >> 24);
        uint2 xw = xb[s];
        float x0 = unlo(xw.x) * norm, x1 = unhi(xw.x) * norm;
        float x2 = unlo(xw.y) * norm, x3 = unhi(xw.y) * norm;
        const float* w = w1 + (size_t)t * 16;   // [2][2][4]
#pragma unroll
        for (int o = 0; o < 4; o++) {
            acc[o]     += x0 * w[o]     + x1 * w[4 + o];
            acc[4 + o] += x2 * w[8 + o] + x3 * w[12 + o];
        }
    }
#pragma unroll
    for (int j = 0; j < 8; j++) {
        acc[j] += __shfl_xor(acc[j], 1);
        acc[j] += __shfl_xor(acc[j], 2);
    }
    if (r != 0) return;
    float4 xn = *(const float4*)(x + (size_t)n * 4);
    float h[8];
#pragma unroll
    for (int j = 0; j < 8; j++) {
        float v = acc[j] + b1[j] + xn.x * root1[j] + xn.y * root1[8 + j]
                + xn.z * root1[16 + j] + xn.w * root1[24 + j];
        h[j] = fmaxf(v, 0.0f);
    }
    float* hf = h1f + (size_t)n * 8;
#pragma unroll
    for (int j = 0; j < 8; j++) hf[j] = h[j];
    h1b[n] = make_uint4(pack2(h[0], h[1]), pack2(h[2], h[3]),
                        pack2(h[4], h[5]), pack2(h[6], h[7]));
}

// ---------------- layer 2: add-aggr + root + bias + relu  (4 lanes/node) ----------------
// in=8 (4x2), out=12 (4x3). writes h2f (fp32) + h2b (bf16x12 padded to 32B)
__global__ __launch_bounds__(256) void layer2_kernel(
        const u32* __restrict__ off, const u32* __restrict__ recs,
        const uint4* __restrict__ h1b,
        const float* __restrict__ h1f, const float* __restrict__ w2,
        const float* __restrict__ root2, const float* __restrict__ b2,
        float* __restrict__ h2f, u32* __restrict__ h2b) {
    int gid = blockIdx.x * 256 + threadIdx.x;
    int n = gid >> 2, r = gid & 3;
    if (n >= NN) return;
    float acc[12];
#pragma unroll
    for (int j = 0; j < 12; j++) acc[j] = 0.0f;

    u32 k0 = off[n], k1 = off[n + 1];
    for (u32 k = k0 + r; k < k1; k += 4) {
        u32 rec = recs[k];
        u32 t = rec & 127u, s = (rec >> 7) & 0x1FFFFu;
        uint4 hw = h1b[s];
        float a0 = unlo(hw.x), a1 = unhi(hw.x), a2 = unlo(hw.y), a3 = unhi(hw.y);
        float a4 = unlo(hw.z), a5 = unhi(hw.z), a6 = unlo(hw.w), a7 = unhi(hw.w);
        const float* w = w2 + (size_t)t * 24;   // [4][2][3]
#pragma unroll
        for (int o = 0; o < 3; o++) {
            acc[o]     += a0 * w[o]      + a1 * w[3 + o];
            acc[3 + o] += a2 * w[6 + o]  + a3 * w[9 + o];
            acc[6 + o] += a4 * w[12 + o] + a5 * w[15 + o];
            acc[9 + o] += a6 * w[18 + o] + a7 * w[21 + o];
        }
    }
#pragma unroll
    for (int j = 0; j < 12; j++) {
        acc[j] += __shfl_xor(acc[j], 1);
        acc[j] += __shfl_xor(acc[j], 2);
    }
    if (r != 0) return;
    const float* hn = h1f + (size_t)n * 8;
    float hv[8];
#pragma unroll
    for (int i = 0; i < 8; i++) hv[i] = hn[i];
    float h[12];
#pragma unroll
    for (int j = 0; j < 12; j++) {
        float v = acc[j] + b2[j];
#pragma unroll
        for (int i = 0; i < 8; i++) v += hv[i] * root2[i * 12 + j];
        h[j] = fmaxf(v, 0.0f);
    }
    float* hf = h2f + (size_t)n * 12;
#pragma unroll
    for (int j = 0; j < 12; j++) hf[j] = h[j];
    u32* hb = h2b + (size_t)n * 8;             // 32B stride, 24B used
    *(uint4*)hb = make_uint4(pack2(h[0], h[1]), pack2(h[2], h[3]),
                             pack2(h[4], h[5]), pack2(h[6], h[7]));
    *(uint2*)(hb + 4) = make_uint2(pack2(h[8], h[9]), pack2(h[10], h[11]));
}

// ---------------- layer 3: mean-aggr + root + bias + log_softmax  (4 lanes/node) ----------------
// in=12 (2x6), out=4 (2x2)
__global__ __launch_bounds__(256) void layer3_kernel(
        const u32* __restrict__ off, const u32* __restrict__ recs,
        const u32* __restrict__ h2b,
        const float* __restrict__ h2f, const float* __restrict__ w3,
        const float* __restrict__ root3, const float* __restrict__ b3,
        float* __restrict__ out) {
    int gid = blockIdx.x * 256 + threadIdx.x;
    int n = gid >> 2, r = gid & 3;
    if (n >= NN) return;
    float acc[4] = {0.0f, 0.0f, 0.0f, 0.0f};
    u32 k0 = off[n], k1 = off[n + 1];
    for (u32 k = k0 + r; k < k1; k += 4) {
        u32 rec = recs[k];
        u32 t = rec & 127u, s = (rec >> 7) & 0x1FFFFu;
        float norm = 1.0f / (float)(rec >> 24);
        const u32* hb = h2b + (size_t)s * 8;
        uint4 q = *(const uint4*)hb;
        uint2 p = *(const uint2*)(hb + 4);
        float hsv[12] = { unlo(q.x), unhi(q.x), unlo(q.y), unhi(q.y),
                          unlo(q.z), unhi(q.z), unlo(q.w), unhi(q.w),
                          unlo(p.x), unhi(p.x), unlo(p.y), unhi(p.y) };
        const float* w = w3 + (size_t)t * 24;   // [2][6][2]
        float m0 = 0.0f, m1 = 0.0f, m2 = 0.0f, m3 = 0.0f;
#pragma unroll
        for (int i = 0; i < 6; i++) {
            m0 += hsv[i] * w[i * 2];          m1 += hsv[i] * w[i * 2 + 1];
            m2 += hsv[6 + i] * w[12 + i * 2]; m3 += hsv[6 + i] * w[12 + i * 2 + 1];
        }
        acc[0] += m0 * norm; acc[1] += m1 * norm;
        acc[2] += m2 * norm; acc[3] += m3 * norm;
    }
#pragma unroll
    for (int j = 0; j < 4; j++) {
        acc[j] += __shfl_xor(acc[j], 1);
        acc[j] += __shfl_xor(acc[j], 2);
    }
    if (r != 0) return;
    const float* hn = h2f + (size_t)n * 12;
    float hv[12];
#pragma unroll
    for (int i = 0; i < 12; i++) hv[i] = hn[i];
    float t4[4];
#pragma unroll
    for (int j = 0; j < 4; j++) {
        float v = acc[j] + b3[j];
#pragma unroll
        for (int i = 0; i < 12; i++) v += hv[i] * root3[i * 4 + j];
        t4[j] = v;
    }
    float m = fmaxf(fmaxf(t4[0], t4[1]), fmaxf(t4[2], t4[3]));
    float s = 0.0f;
#pragma unroll
    for (int j = 0; j < 4; j++) s += __expf(t4[j] - m);
    float lse = m + __logf(s);
    float* o = out + (size_t)n * 4;
#pragma unroll
    for (int j = 0; j < 4; j++) o[j] = t4[j] - lse;
}

extern "C" void kernel_launch(void* const* d_in, const int* in_sizes, int n_in,
                              void* d_out, int out_size, void* d_ws, size_t ws_size,
                              hipStream_t stream) {
    const float* x     = (const float*)d_in[0];
    const int*   ei    = (const int*)d_in[1];   // [2, E]
    const int*   etype = (const int*)d_in[2];
    const float* w1    = (const float*)d_in[3];
    const float* root1 = (const float*)d_in[4];
    const float* b1    = (const float*)d_in[5];
    const float* w2    = (const float*)d_in[6];
    const float* root2 = (const float*)d_in[7];
    const float* b2    = (const float*)d_in[8];
    const float* w3    = (const float*)d_in[9];
    const float* root3 = (const float*)d_in[10];
    const float* b3    = (const float*)d_in[11];
    float* out = (float*)d_out;

    const int* src = ei;
    const int* dst = ei + NE;

    // workspace layout (bytes):
    //   ccnt    : [NB]    u32  @ 0           (pad 1,600)
    //   ccursor : [NB]    u32  @ 1,600       (pad 3,200)
    //   coff    : [NB+1]  u32  @ 3,200       (pad 4,800)
    //   off     : [NN+1]  u32  @ 4,800       (ends 404,804, pad 406,400)
    //   tmp     : [NE]    u32  @ 406,400     (12,800,000)
    //   recs    : [NE]    u32  @ 13,206,400  (12,800,000)
    //   xb      : [NN]    8B   @ 26,006,400  (   800,000)
    //   h1f     : [NN*8]  f32  @ 26,806,400  ( 3,200,000)
    //   h1b     : [NN]    16B  @ 30,006,400  ( 1,600,000)
    //   h2f     : [NN*12] f32  @ 31,606,400  ( 4,800,000)
    //   h2b     : [NN]    32B  @ 36,406,400  ( 3,200,000)  -> total 39,606,400
    char* ws = (char*)d_ws;
    u32*   ccnt    = (u32*)ws;
    u32*   ccursor = (u32*)(ws + 1600);
    u32*   coff    = (u32*)(ws + 3200);
    u32*   off     = (u32*)(ws + 4800);
    u32*   tmp     = (u32*)(ws + 406400);
    u32*   recs    = (u32*)(ws + 13206400);
    uint2* xb      = (uint2*)(ws + 26006400);
    float* h1f     = (float*)(ws + 26806400);
    uint4* h1b     = (uint4*)(ws + 30006400);
    float* h2f     = (float*)(ws + 31606400);
    u32*   h2b     = (u32*)(ws + 36406400);

    hipMemsetAsync(ccnt, 0, NB * sizeof(u32), stream);

    dim3 blk(256);
    dim3 pgrid((NE + CH - 1) / CH);          // 391
    dim3 ngrid(NB);                          // 391
    dim3 lgrid((NN * 4 + 255) / 256);        // 1563 (4 lanes/node)

    coarse_count_kernel<<<pgrid, blk, 0, stream>>>(dst, ccnt);
    scan_coff_kernel<<<1, 512, 0, stream>>>(ccnt, coff, ccursor);
    pass1_kernel<<<pgrid, blk, 0, stream>>>(src, dst, etype, ccursor, tmp);
    pass2_kernel<<<ngrid, blk, 0, stream>>>(tmp, coff, off, recs, x, xb);
    layer1_kernel<<<lgrid, blk, 0, stream>>>(off, recs, xb, x, w1, root1, b1, h1f, h1b);
    layer2_kernel<<<lgrid, blk, 0, stream>>>(off, recs, h1b, h1f, w2, root2, b2, h2f, h2b);
    layer3_kernel<<<lgrid, blk, 0, stream>>>(off, recs, h2b, h2f, w3, root3, b3, out);
}

// Round 7
// 310.364 us; speedup vs baseline: 13.1693x; 1.0666x over previous
//
#include <hip/hip_runtime.h>
#include <math.h>

#define NN 100000
#define NE 3200000
#define NR 90
#define NB 391          // ceil(NN/256): buckets of 256 nodes (dst>>8)
#define CH 4096         // edges per block in partition passes
#define NCHUNK 782      // ceil(NE/CH)

typedef unsigned int u32;
typedef unsigned short u16;

__device__ inline u32 pack2(float a, float b) {       // bf16(a) lo16, bf16(b) hi16 (RNE)
    u32 ua = __float_as_uint(a); ua += 0x7FFFu + ((ua >> 16) & 1u);
    u32 ub = __float_as_uint(b); ub += 0x7FFFu + ((ub >> 16) & 1u);
    return (ua >> 16) | (ub & 0xFFFF0000u);
}
__device__ inline float unlo(u32 w) { return __uint_as_float(w << 16); }
__device__ inline float unhi(u32 w) { return __uint_as_float(w & 0xFFFF0000u); }

// ---------------- coarse histogram: bucket = dst >> 8 ----------------
__global__ __launch_bounds__(256) void coarse_count_kernel(const int* __restrict__ dst,
                                                           u32* __restrict__ ccnt) {
    __shared__ u32 bh[NB];
    int tid = threadIdx.x;
    for (int b = tid; b < NB; b += 256) bh[b] = 0;
    __syncthreads();
    int c0 = blockIdx.x * CH;
    int c1 = c0 + CH; if (c1 > NE) c1 = NE;
    for (int e = c0 + tid; e < c1; e += 256)
        atomicAdd(&bh[(u32)dst[e] >> 8], 1u);
    __syncthreads();
    for (int b = tid; b < NB; b += 256) {
        u32 c = bh[b];
        if (c) atomicAdd(&ccnt[b], c);
    }
}

// ---------------- exclusive scan of NB coarse counts (1 block) ----------------
__global__ __launch_bounds__(512) void scan_coff_kernel(const u32* __restrict__ ccnt,
                                                        u32* __restrict__ coff,
                                                        u32* __restrict__ ccursor) {
    __shared__ u32 sh[512];
    int tid = threadIdx.x;
    sh[tid] = (tid < NB) ? ccnt[tid] : 0u;
    __syncthreads();
#pragma unroll
    for (int ofs = 1; ofs < 512; ofs <<= 1) {
        u32 v = (tid >= ofs) ? sh[tid - ofs] : 0u;
        __syncthreads();
        sh[tid] += v;
        __syncthreads();
    }
    u32 excl = (tid == 0) ? 0u : sh[tid - 1];
    if (tid < NB) { coff[tid] = excl; ccursor[tid] = excl; }
    if (tid == 0) coff[NB] = NE;
}

// ---------------- pass 1: LDS-staged coarse partition, coalesced run writes ----------------
// tmp entry: (dst&255)<<24 | src<<7 | et
__global__ __launch_bounds__(512) void pass1_kernel(const int* __restrict__ src,
                                                    const int* __restrict__ dst,
                                                    const int* __restrict__ et,
                                                    u32* __restrict__ ccursor,
                                                    u32* __restrict__ tmp) {
    __shared__ u32 cntA[NB];       // per-bucket count in this chunk
    __shared__ u32 lstart[NB];     // local exclusive prefix
    __shared__ u32 lcur[NB];       // local cursor
    __shared__ u32 delta[NB];      // gbase - lstart
    __shared__ u32 scanS[512];
    __shared__ u32 lrecs[CH];      // bucket-sorted records (chunk-local)
    __shared__ u16 lbid[CH];       // bucket id per sorted slot
    int tid = threadIdx.x;
    int c0 = blockIdx.x * CH;
    int c1 = c0 + CH; if (c1 > NE) c1 = NE;
    int nloc = c1 - c0;

    if (tid < NB) cntA[tid] = 0;
    __syncthreads();

    // A: local bucket histogram
    for (int e = c0 + tid; e < c1; e += 512)
        atomicAdd(&cntA[(u32)dst[e] >> 8], 1u);
    __syncthreads();

    // B: exclusive scan of cntA (512-wide Hillis-Steele)
    scanS[tid] = (tid < NB) ? cntA[tid] : 0u;
    __syncthreads();
#pragma unroll
    for (int ofs = 1; ofs < 512; ofs <<= 1) {
        u32 v = (tid >= ofs) ? scanS[tid - ofs] : 0u;
        __syncthreads();
        scanS[tid] += v;
        __syncthreads();
    }
    if (tid < NB) {
        u32 excl = (tid == 0) ? 0u : scanS[tid - 1];
        lstart[tid] = excl;
        lcur[tid] = excl;
        u32 c = cntA[tid];
        delta[tid] = c ? (atomicAdd(&ccursor[tid], c) - excl) : 0u;   // C: reserve run
    }
    __syncthreads();

    // D: scatter into LDS in bucket order
    for (int e = c0 + tid; e < c1; e += 512) {
        u32 d = (u32)dst[e];
        u32 b = d >> 8;
        u32 pos = atomicAdd(&lcur[b], 1u);
        lrecs[pos] = ((d & 255u) << 24) | ((u32)src[e] << 7) | (u32)et[e];
        lbid[pos] = (u16)b;
    }
    __syncthreads();

    // E: coalesced write-out (consecutive k -> consecutive addresses within runs)
    for (int k = tid; k < nloc; k += 512)
        tmp[delta[lbid[k]] + k] = lrecs[k];
}

// ---------------- pass 2: per-bucket fine sort; recs gets cnt<<24 | src<<7 | et ----------------
__global__ __launch_bounds__(512) void pass2_kernel(const u32* __restrict__ tmp,
                                                    const u32* __restrict__ coff,
                                                    u32* __restrict__ off,
                                                    u32* __restrict__ recs,
                                                    const float* __restrict__ x,
                                                    uint2* __restrict__ xb) {
    __shared__ u32 dh[256];          // per-node degree
    __shared__ u32 lcur[256];        // per-node cursor (relative)
    __shared__ u32 cnt32[256 * 23];  // per-(node,rel) u8 counts packed 4/word
    __shared__ u32 sh[256];
    int tid = threadIdx.x;
    int b = blockIdx.x;
    u32 r0 = coff[b], r1 = coff[b + 1];

    if (tid < 256) dh[tid] = 0;
    for (int i = tid; i < 256 * 23; i += 512) cnt32[i] = 0;
    __syncthreads();

    // A: per-node degrees
    for (u32 k = r0 + tid; k < r1; k += 512)
        atomicAdd(&dh[tmp[k] >> 24], 1u);
    __syncthreads();

    // B: inclusive scan of dh (256 entries)
    if (tid < 256) sh[tid] = dh[tid];
    __syncthreads();
#pragma unroll
    for (int ofs = 1; ofs < 256; ofs <<= 1) {
        u32 v = (tid >= ofs && tid < 256) ? sh[tid - ofs] : 0u;
        __syncthreads();
        if (tid < 256) sh[tid] += v;
        __syncthreads();
    }
    int n = b * 256 + tid;
    if (tid < 256) {
        u32 excl = (tid == 0) ? 0u : sh[tid - 1];
        if (n < NN) off[n] = r0 + excl;
        lcur[tid] = excl;
    }
    if (b == NB - 1 && tid == 0) off[NN] = NE;
    __syncthreads();

    // C: fine scatter into this bucket's recs window + per-(node,rel) counts
    for (u32 k = r0 + tid; k < r1; k += 512) {
        u32 v = tmp[k];
        u32 ln = v >> 24;
        u32 rec = v & 0xFFFFFFu;          // src<<7 | et
        u32 rel = v & 127u;
        u32 pos = atomicAdd(&lcur[ln], 1u);
        recs[r0 + pos] = rec;
        atomicAdd(&cnt32[ln * 23 + (rel >> 2)], 1u << ((rel & 3u) * 8u));
    }
    __syncthreads();

    // D: embed per-(node,rel) count into the top byte of each rec; pack xb
    if (tid < 256 && n < NN) {
        u32 start = (tid == 0) ? 0u : sh[tid - 1];
        u32 end = sh[tid];
        for (u32 j = start; j < end; j++) {
            u32 rel = recs[r0 + j] & 127u;
            u32 c = (cnt32[tid * 23 + (rel >> 2)] >> ((rel & 3u) * 8u)) & 255u;
            recs[r0 + j] |= c << 24;
        }
        float4 xv = *(const float4*)(x + (size_t)n * 4);
        xb[n] = make_uint2(pack2(xv.x, xv.y), pack2(xv.z, xv.w));
    }
}

// ---------------- layer 1: mean-aggr + root + bias + relu  (4 lanes/node) ----------------
__global__ __launch_bounds__(256) void layer1_kernel(
        const u32* __restrict__ off, const u32* __restrict__ recs,
        const uint2* __restrict__ xb,
        const float* __restrict__ x, const float* __restrict__ w1,
        const float* __restrict__ root1, const float* __restrict__ b1,
        float* __restrict__ h1f, uint4* __restrict__ h1b) {
    int gid = blockIdx.x * 256 + threadIdx.x;
    int n = gid >> 2, r = gid & 3;
    if (n >= NN) return;
    float acc[8];
#pragma unroll
    for (int j = 0; j < 8; j++) acc[j] = 0.0f;

    u32 k0 = off[n], k1 = off[n + 1];
    for (u32 k = k0 + r; k < k1; k += 4) {
        u32 rec = recs[k];
        u32 t = rec & 127u, s = (rec >> 7) & 0x1FFFFu;
        float norm = 1.0f / (float)(rec >> 24);
        uint2 xw = xb[s];
        float x0 = unlo(xw.x) * norm, x1 = unhi(xw.x) * norm;
        float x2 = unlo(xw.y) * norm, x3 = unhi(xw.y) * norm;
        const float* w = w1 + (size_t)t * 16;   // [2][2][4]
#pragma unroll
        for (int o = 0; o < 4; o++) {
            acc[o]     += x0 * w[o]     + x1 * w[4 + o];
            acc[4 + o] += x2 * w[8 + o] + x3 * w[12 + o];
        }
    }
#pragma unroll
    for (int j = 0; j < 8; j++) {
        acc[j] += __shfl_xor(acc[j], 1);
        acc[j] += __shfl_xor(acc[j], 2);
    }
    if (r != 0) return;
    float4 xn = *(const float4*)(x + (size_t)n * 4);
    float h[8];
#pragma unroll
    for (int j = 0; j < 8; j++) {
        float v = acc[j] + b1[j] + xn.x * root1[j] + xn.y * root1[8 + j]
                + xn.z * root1[16 + j] + xn.w * root1[24 + j];
        h[j] = fmaxf(v, 0.0f);
    }
    float* hf = h1f + (size_t)n * 8;
#pragma unroll
    for (int j = 0; j < 8; j++) hf[j] = h[j];
    h1b[n] = make_uint4(pack2(h[0], h[1]), pack2(h[2], h[3]),
                        pack2(h[4], h[5]), pack2(h[6], h[7]));
}

// ---------------- layer 2: add-aggr + root + bias + relu  (4 lanes/node) ----------------
__global__ __launch_bounds__(256) void layer2_kernel(
        const u32* __restrict__ off, const u32* __restrict__ recs,
        const uint4* __restrict__ h1b,
        const float* __restrict__ h1f, const float* __restrict__ w2,
        const float* __restrict__ root2, const float* __restrict__ b2,
        float* __restrict__ h2f, u32* __restrict__ h2b) {
    int gid = blockIdx.x * 256 + threadIdx.x;
    int n = gid >> 2, r = gid & 3;
    if (n >= NN) return;
    float acc[12];
#pragma unroll
    for (int j = 0; j < 12; j++) acc[j] = 0.0f;

    u32 k0 = off[n], k1 = off[n + 1];
    for (u32 k = k0 + r; k < k1; k += 4) {
        u32 rec = recs[k];
        u32 t = rec & 127u, s = (rec >> 7) & 0x1FFFFu;
        uint4 hw = h1b[s];
        float a0 = unlo(hw.x), a1 = unhi(hw.x), a2 = unlo(hw.y), a3 = unhi(hw.y);
        float a4 = unlo(hw.z), a5 = unhi(hw.z), a6 = unlo(hw.w), a7 = unhi(hw.w);
        const float* w = w2 + (size_t)t * 24;   // [4][2][3]
#pragma unroll
        for (int o = 0; o < 3; o++) {
            acc[o]     += a0 * w[o]      + a1 * w[3 + o];
            acc[3 + o] += a2 * w[6 + o]  + a3 * w[9 + o];
            acc[6 + o] += a4 * w[12 + o] + a5 * w[15 + o];
            acc[9 + o] += a6 * w[18 + o] + a7 * w[21 + o];
        }
    }
#pragma unroll
    for (int j = 0; j < 12; j++) {
        acc[j] += __shfl_xor(acc[j], 1);
        acc[j] += __shfl_xor(acc[j], 2);
    }
    if (r != 0) return;
    const float* hn = h1f + (size_t)n * 8;
    float hv[8];
#pragma unroll
    for (int i = 0; i < 8; i++) hv[i] = hn[i];
    float h[12];
#pragma unroll
    for (int j = 0; j < 12; j++) {
        float v = acc[j] + b2[j];
#pragma unroll
        for (int i = 0; i < 8; i++) v += hv[i] * root2[i * 12 + j];
        h[j] = fmaxf(v, 0.0f);
    }
    float* hf = h2f + (size_t)n * 12;
#pragma unroll
    for (int j = 0; j < 12; j++) hf[j] = h[j];
    u32* hb = h2b + (size_t)n * 8;             // 32B stride, 24B used
    *(uint4*)hb = make_uint4(pack2(h[0], h[1]), pack2(h[2], h[3]),
                             pack2(h[4], h[5]), pack2(h[6], h[7]));
    *(uint2*)(hb + 4) = make_uint2(pack2(h[8], h[9]), pack2(h[10], h[11]));
}

// ---------------- layer 3: mean-aggr + root + bias + log_softmax  (4 lanes/node) ----------------
__global__ __launch_bounds__(256) void layer3_kernel(
        const u32* __restrict__ off, const u32* __restrict__ recs,
        const u32* __restrict__ h2b,
        const float* __restrict__ h2f, const float* __restrict__ w3,
        const float* __restrict__ root3, const float* __restrict__ b3,
        float* __restrict__ out) {
    int gid = blockIdx.x * 256 + threadIdx.x;
    int n = gid >> 2, r = gid & 3;
    if (n >= NN) return;
    float acc[4] = {0.0f, 0.0f, 0.0f, 0.0f};
    u32 k0 = off[n], k1 = off[n + 1];
    for (u32 k = k0 + r; k < k1; k += 4) {
        u32 rec = recs[k];
        u32 t = rec & 127u, s = (rec >> 7) & 0x1FFFFu;
        float norm = 1.0f / (float)(rec >> 24);
        const u32* hb = h2b + (size_t)s * 8;
        uint4 q = *(const uint4*)hb;
        uint2 p = *(const uint2*)(hb + 4);
        float hsv[12] = { unlo(q.x), unhi(q.x), unlo(q.y), unhi(q.y),
                          unlo(q.z), unhi(q.z), unlo(q.w), unhi(q.w),
                          unlo(p.x), unhi(p.x), unlo(p.y), unhi(p.y) };
        const float* w = w3 + (size_t)t * 24;   // [2][6][2]
        float m0 = 0.0f, m1 = 0.0f, m2 = 0.0f, m3 = 0.0f;
#pragma unroll
        for (int i = 0; i < 6; i++) {
            m0 += hsv[i] * w[i * 2];          m1 += hsv[i] * w[i * 2 + 1];
            m2 += hsv[6 + i] * w[12 + i * 2]; m3 += hsv[6 + i] * w[12 + i * 2 + 1];
        }
        acc[0] += m0 * norm; acc[1] += m1 * norm;
        acc[2] += m2 * norm; acc[3] += m3 * norm;
    }
#pragma unroll
    for (int j = 0; j < 4; j++) {
        acc[j] += __shfl_xor(acc[j], 1);
        acc[j] += __shfl_xor(acc[j], 2);
    }
    if (r != 0) return;
    const float* hn = h2f + (size_t)n * 12;
    float hv[12];
#pragma unroll
    for (int i = 0; i < 12; i++) hv[i] = hn[i];
    float t4[4];
#pragma unroll
    for (int j = 0; j < 4; j++) {
        float v = acc[j] + b3[j];
#pragma unroll
        for (int i = 0; i < 12; i++) v += hv[i] * root3[i * 4 + j];
        t4[j] = v;
    }
    float m = fmaxf(fmaxf(t4[0], t4[1]), fmaxf(t4[2], t4[3]));
    float s = 0.0f;
#pragma unroll
    for (int j = 0; j < 4; j++) s += __expf(t4[j] - m);
    float lse = m + __logf(s);
    float* o = out + (size_t)n * 4;
#pragma unroll
    for (int j = 0; j < 4; j++) o[j] = t4[j] - lse;
}

extern "C" void kernel_launch(void* const* d_in, const int* in_sizes, int n_in,
                              void* d_out, int out_size, void* d_ws, size_t ws_size,
                              hipStream_t stream) {
    const float* x     = (const float*)d_in[0];
    const int*   ei    = (const int*)d_in[1];   // [2, E]
    const int*   etype = (const int*)d_in[2];
    const float* w1    = (const float*)d_in[3];
    const float* root1 = (const float*)d_in[4];
    const float* b1    = (const float*)d_in[5];
    const float* w2    = (const float*)d_in[6];
    const float* root2 = (const float*)d_in[7];
    const float* b2    = (const float*)d_in[8];
    const float* w3    = (const float*)d_in[9];
    const float* root3 = (const float*)d_in[10];
    const float* b3    = (const float*)d_in[11];
    float* out = (float*)d_out;

    const int* src = ei;
    const int* dst = ei + NE;

    // workspace layout (bytes):
    //   ccnt    : [NB]    u32  @ 0           (pad 1,600)
    //   ccursor : [NB]    u32  @ 1,600       (pad 3,200)
    //   coff    : [NB+1]  u32  @ 3,200       (pad 4,800)
    //   off     : [NN+1]  u32  @ 4,800       (ends 404,804, pad 406,400)
    //   tmp     : [NE]    u32  @ 406,400     (12,800,000)
    //   recs    : [NE]    u32  @ 13,206,400  (12,800,000)
    //   xb      : [NN]    8B   @ 26,006,400  (   800,000)
    //   h1f     : [NN*8]  f32  @ 26,806,400  ( 3,200,000)
    //   h1b     : [NN]    16B  @ 30,006,400  ( 1,600,000)
    //   h2f     : [NN*12] f32  @ 31,606,400  ( 4,800,000)
    //   h2b     : [NN]    32B  @ 36,406,400  ( 3,200,000)  -> total 39,606,400
    char* ws = (char*)d_ws;
    u32*   ccnt    = (u32*)ws;
    u32*   ccursor = (u32*)(ws + 1600);
    u32*   coff    = (u32*)(ws + 3200);
    u32*   off     = (u32*)(ws + 4800);
    u32*   tmp     = (u32*)(ws + 406400);
    u32*   recs    = (u32*)(ws + 13206400);
    uint2* xb      = (uint2*)(ws + 26006400);
    float* h1f     = (float*)(ws + 26806400);
    uint4* h1b     = (uint4*)(ws + 30006400);
    float* h2f     = (float*)(ws + 31606400);
    u32*   h2b     = (u32*)(ws + 36406400);

    hipMemsetAsync(ccnt, 0, NB * sizeof(u32), stream);

    dim3 pgrid(NCHUNK);                      // 782
    dim3 ngrid(NB);                          // 391
    dim3 lgrid((NN * 4 + 255) / 256);        // 1563 (4 lanes/node)

    coarse_count_kernel<<<pgrid, 256, 0, stream>>>(dst, ccnt);
    scan_coff_kernel<<<1, 512, 0, stream>>>(ccnt, coff, ccursor);
    pass1_kernel<<<pgrid, 512, 0, stream>>>(src, dst, etype, ccursor, tmp);
    pass2_kernel<<<ngrid, 512, 0, stream>>>(tmp, coff, off, recs, x, xb);
    layer1_kernel<<<lgrid, 256, 0, stream>>>(off, recs, xb, x, w1, root1, b1, h1f, h1b);
    layer2_kernel<<<lgrid, 256, 0, stream>>>(off, recs, h1b, h1f, w2, root2, b2, h2f, h2b);
    layer3_kernel<<<lgrid, 256, 0, stream>>>(off, recs, h2b, h2f, w3, root3, b3, out);
}